// Round 1
// baseline (572.708 us; speedup 1.0000x reference)
//
#include <hip/hip_runtime.h>

// AREMA envelope follower: y_t = y_{t-1} + alpha*(x_t - y_{t-1}),
// alpha = ATTACK if (x_t - y_{t-1}) > 0 else RELEASE.
// Segmented-scan with warm-up: the step map is a contraction with factor
// (1-RELEASE) = 0.9802, so starting a segment WARM=384 steps early from y=0
// bounds the error by 2.2 * 0.9802^384 ~= 1e-3 << 4.4e-2 threshold.

typedef float v4 __attribute__((ext_vector_type(4)));

#define T_LEN   16384
#define F_DIM   512
#define FV      128        // F_DIM / 4 (float4 columns)
#define SEGS    16
#define SEG_LEN 1024       // T_LEN / SEGS
#define WARM    384        // warm-up steps; multiple of 2*UNROLL
#define UNROLL  8

#define ATTACK_C  0.18126924692201818f   // 1 - exp(-0.001/0.005)
#define RELEASE_C 0.019801326696744665f  // 1 - exp(-0.001/0.05)

__device__ __forceinline__ float astep(float x, float y) {
    float d = x - y;
    float alpha = (d > 0.0f) ? ATTACK_C : RELEASE_C;
    return fmaf(alpha, d, y);   // == alpha*x + (1-alpha)*y
}

__global__ __launch_bounds__(64) void arema_kernel(const float* __restrict__ xg,
                                                   float* __restrict__ yg) {
    const int f4 = blockIdx.x * 64 + threadIdx.x;   // 0..FV-1
    const int s  = blockIdx.y;                      // segment
    const int b  = blockIdx.z;                      // batch

    const int sL    = s * SEG_LEN;
    const int begin = (s == 0) ? 0 : (sL - WARM);
    const int end   = sL + SEG_LEN;

    const v4* __restrict__ xin = (const v4*)xg + (size_t)b * T_LEN * FV + f4;
    v4* __restrict__ yout      = (v4*)yg       + (size_t)b * T_LEN * FV + f4;

    float y0 = 0.f, y1 = 0.f, y2 = 0.f, y3 = 0.f;
    v4 bufA[UNROLL], bufB[UNROLL];

    int t = begin;
#pragma unroll
    for (int i = 0; i < UNROLL; ++i)
        bufA[i] = xin[(size_t)(t + i) * FV];

    const int nch = (end - begin) / UNROLL;   // 128 (s==0) or 176 — always even

    for (int c = 0; c < nch; c += 2) {
        // prefetch chunk c+1 into bufB (stays in flight while computing bufA)
#pragma unroll
        for (int i = 0; i < UNROLL; ++i)
            bufB[i] = xin[(size_t)(t + UNROLL + i) * FV];

        // compute chunk c from bufA
        {
            const bool wr = (t >= sL);   // block-uniform: warm-up vs live
#pragma unroll
            for (int i = 0; i < UNROLL; ++i) {
                v4 xv = bufA[i];
                y0 = astep(xv.x, y0);
                y1 = astep(xv.y, y1);
                y2 = astep(xv.z, y2);
                y3 = astep(xv.w, y3);
                if (wr) {
                    v4 o = {y0, y1, y2, y3};
                    __builtin_nontemporal_store(o, &yout[(size_t)(t + i) * FV]);
                }
            }
        }

        // prefetch chunk c+2 into bufA (dummy re-read of `begin` on the last pair)
        const int tp = (c + 2 < nch) ? (t + 2 * UNROLL) : begin;
#pragma unroll
        for (int i = 0; i < UNROLL; ++i)
            bufA[i] = xin[(size_t)(tp + i) * FV];

        // compute chunk c+1 from bufB
        {
            const int tb = t + UNROLL;
            const bool wr = (tb >= sL);
#pragma unroll
            for (int i = 0; i < UNROLL; ++i) {
                v4 xv = bufB[i];
                y0 = astep(xv.x, y0);
                y1 = astep(xv.y, y1);
                y2 = astep(xv.z, y2);
                y3 = astep(xv.w, y3);
                if (wr) {
                    v4 o = {y0, y1, y2, y3};
                    __builtin_nontemporal_store(o, &yout[(size_t)(tb + i) * FV]);
                }
            }
        }

        t += 2 * UNROLL;
    }
}

extern "C" void kernel_launch(void* const* d_in, const int* in_sizes, int n_in,
                              void* d_out, int out_size, void* d_ws, size_t ws_size,
                              hipStream_t stream) {
    const float* x = (const float*)d_in[0];
    float* y = (float*)d_out;
    const int B = in_sizes[0] / (T_LEN * F_DIM);   // = 8
    dim3 grid(FV / 64, SEGS, B);                   // 2 x 16 x 8 = 256 blocks, 1 wave each
    arema_kernel<<<grid, dim3(64, 1, 1), 0, stream>>>(x, y);
}

// Round 2
// 461.925 us; speedup vs baseline: 1.2398x; 1.2398x over previous
//
#include <hip/hip_runtime.h>

// AREMA envelope follower: y_t = y_{t-1} + alpha*(x_t - y_{t-1}),
// alpha = ATTACK if (x_t - y_{t-1}) > 0 else RELEASE.
// Segmented scan with warm-up: step map is a contraction (factor <= 0.9802),
// so starting each segment WARM=256 steps early from y=0 bounds the error by
// 2.2 * 0.9802^256 ~= 0.013 << 0.044 threshold.
//
// Round-2 change: scalar (1 float/thread) + SEGS=32 -> 2048 waves (8/CU)
// instead of 256 waves (1/CU). Round 1 was latency-bound at 1.58 TB/s.

#define T_LEN   16384
#define F_DIM   512
#define SEGS    32
#define SEG_LEN 512        // T_LEN / SEGS
#define WARM    256        // multiple of 2*UNROLL
#define UNROLL  16

#define ATTACK_C  0.18126924692201818f   // 1 - exp(-0.001/0.005)
#define RELEASE_C 0.019801326696744665f  // 1 - exp(-0.001/0.05)

__device__ __forceinline__ float astep(float x, float y) {
    float d = x - y;
    float alpha = (d > 0.0f) ? ATTACK_C : RELEASE_C;
    return fmaf(alpha, d, y);   // == alpha*x + (1-alpha)*y
}

__global__ __launch_bounds__(256) void arema_kernel(const float* __restrict__ xg,
                                                    float* __restrict__ yg) {
    const int f = blockIdx.x * 256 + threadIdx.x;   // 0..F_DIM-1
    const int s = blockIdx.y;                       // segment
    const int b = blockIdx.z;                       // batch

    const int sL    = s * SEG_LEN;
    const int begin = (s == 0) ? 0 : (sL - WARM);
    const int end   = sL + SEG_LEN;

    const float* __restrict__ xin = xg + (size_t)b * T_LEN * F_DIM + f;
    float* __restrict__ yout      = yg + (size_t)b * T_LEN * F_DIM + f;

    float y = 0.f;
    float bufA[UNROLL], bufB[UNROLL];

    int t = begin;
#pragma unroll
    for (int i = 0; i < UNROLL; ++i)
        bufA[i] = xin[(size_t)(t + i) * F_DIM];

    const int nch = (end - begin) / UNROLL;   // 32 (s==0) or 48 — always even

    for (int c = 0; c < nch; c += 2) {
        // prefetch chunk c+1 into bufB (in flight while computing bufA)
#pragma unroll
        for (int i = 0; i < UNROLL; ++i)
            bufB[i] = xin[(size_t)(t + UNROLL + i) * F_DIM];

        // compute chunk c from bufA
        {
            const bool wr = (t >= sL);   // uniform: warm-up vs live
#pragma unroll
            for (int i = 0; i < UNROLL; ++i) {
                y = astep(bufA[i], y);
                if (wr)
                    __builtin_nontemporal_store(y, &yout[(size_t)(t + i) * F_DIM]);
            }
        }

        // prefetch chunk c+2 into bufA (dummy re-read of `begin` on last pair)
        const int tp = (c + 2 < nch) ? (t + 2 * UNROLL) : begin;
#pragma unroll
        for (int i = 0; i < UNROLL; ++i)
            bufA[i] = xin[(size_t)(tp + i) * F_DIM];

        // compute chunk c+1 from bufB
        {
            const int tb = t + UNROLL;
            const bool wr = (tb >= sL);
#pragma unroll
            for (int i = 0; i < UNROLL; ++i) {
                y = astep(bufB[i], y);
                if (wr)
                    __builtin_nontemporal_store(y, &yout[(size_t)(tb + i) * F_DIM]);
            }
        }

        t += 2 * UNROLL;
    }
}

extern "C" void kernel_launch(void* const* d_in, const int* in_sizes, int n_in,
                              void* d_out, int out_size, void* d_ws, size_t ws_size,
                              hipStream_t stream) {
    const float* x = (const float*)d_in[0];
    float* y = (float*)d_out;
    const int B = in_sizes[0] / (T_LEN * F_DIM);    // = 8
    dim3 grid(F_DIM / 256, SEGS, B);                // 2 x 32 x 8 = 512 blocks x 4 waves
    arema_kernel<<<grid, dim3(256, 1, 1), 0, stream>>>(x, y);
}